// Round 8
// baseline (391.225 us; speedup 1.0000x reference)
//
#include <hip/hip_runtime.h>
#include <math.h>

typedef __attribute__((ext_vector_type(4))) float f32x4;
typedef __attribute__((ext_vector_type(8))) _Float16 f16x8;
typedef __attribute__((ext_vector_type(4))) _Float16 f16x4;

#define NB 128
#define NQ 128
#define NC 1024
#define ND 1024

static __device__ __forceinline__ f16x4 cvt4(float4 v) {
  auto lo = __builtin_amdgcn_cvt_pkrtz(v.x, v.y);   // __fp16 ext_vector(2)
  auto hi = __builtin_amdgcn_cvt_pkrtz(v.z, v.w);
  return (f16x4){(_Float16)lo[0], (_Float16)lo[1],
                 (_Float16)hi[0], (_Float16)hi[1]};
}
static __device__ __forceinline__ f16x4 cvtT(float a, float b, float c, float d) {
  auto lo = __builtin_amdgcn_cvt_pkrtz(a, b);
  auto hi = __builtin_amdgcn_cvt_pkrtz(c, d);
  return (f16x4){(_Float16)lo[0], (_Float16)lo[1],
                 (_Float16)hi[0], (_Float16)hi[1]};
}

// XCD-grouping remap: linear L = x + 8*y, XCD = L%8 (8 XCDs, round-robin).
// b = (L&7) + 8*(L>>6), tile = (L>>3)&7  ->  all 8 tile-blocks of a given b
// are L≡b (mod 8): same XCD, adjacent in dispatch -> qry[b]/P[b] L2-shared.
static __device__ __forceinline__ void remap(int& b, int& tile) {
  const int L = blockIdx.x + ((int)gridDim.x) * blockIdx.y;
  b = (L & 7) + 8 * (L >> 6);
  tile = (L >> 3) & 7;
}

// ---------------------------------------------------------------------------
// K1: E[b][q][c] = exp(9*lrelu(S)/(||lrelu(S)||_q + 1e-8))  (fp16, into out_w
//     scratch) + per-tile colsum partials ps.  S[c][q]=sum_d ctx[c][d]qry[q][d]
// Depth-2 pipeline on the HBM-cold ctx stream (raA/raB ping-pong, static
// unroll), depth-1 on L2-hot qry. 2 k-chunks (BK=64 each) per loop iter.
// ---------------------------------------------------------------------------
__global__ __launch_bounds__(256, 2) void k1_logits_exp(
    const float* __restrict__ qry, const float* __restrict__ ctx,
    _Float16* __restrict__ Ew, float* __restrict__ psw,
    float* __restrict__ outq)
{
  __shared__ _Float16 As[128][72];   // context rows (c), k contiguous
  __shared__ _Float16 Bs[128][72];   // query rows (q)
  __shared__ float nrm[2][128];      // per-c-row sumsq partials (by wn)
  __shared__ float sps[2][128];      // per-q colsum partials (by wm)

  int b, ct;
  remap(b, ct);
  const int c0 = ct * 128;
  const int t  = threadIdx.x;
  const int lane = t & 63, wave = t >> 6;
  const int wm = wave >> 1, wn = wave & 1;
  const int g = lane >> 4, l15 = lane & 15;
  const int lrow = t >> 4, lcol = (t & 15) * 4;

  const float* ctxB = ctx + (size_t)b * NC * ND;
  const float* qB   = qry + (size_t)b * NQ * ND;

  f32x4 acc[4][4] = {};
  float4 raA[8], raB[8], rb[8];

  auto loadCtx = [&](int k0, float4 (&ra)[8]) {
#pragma unroll
    for (int r = 0; r < 8; ++r)
      ra[r] = *(const float4*)&ctxB[(size_t)(c0 + r*16 + lrow) * ND + k0 + lcol];
  };
  auto loadQ = [&](int k0) {
#pragma unroll
    for (int r = 0; r < 8; ++r)
      rb[r] = *(const float4*)&qB[(size_t)(r*16 + lrow) * ND + k0 + lcol];
  };
  auto mfmaPhase = [&]() {
#pragma unroll
    for (int kk = 0; kk < 2; ++kk) {
      f16x8 af[4], bf[4];
#pragma unroll
      for (int m = 0; m < 4; ++m)
        af[m] = *(const f16x8*)&As[wm*64 + m*16 + l15][kk*32 + g*8];
#pragma unroll
      for (int n = 0; n < 4; ++n)
        bf[n] = *(const f16x8*)&Bs[wn*64 + n*16 + l15][kk*32 + g*8];
#pragma unroll
      for (int m = 0; m < 4; ++m)
#pragma unroll
        for (int n = 0; n < 4; ++n)
          acc[m][n] = __builtin_amdgcn_mfma_f32_16x16x32_f16(af[m], bf[n], acc[m][n], 0, 0, 0);
    }
  };
  float* oq = outq + (size_t)b * NQ * ND;

  loadCtx(0, raA);
  loadQ(0);
  loadCtx(64, raB);

  for (int k0 = 0; k0 < ND; k0 += 128) {
    // ---- substep A: tile k0 (ctx from raA, qry from rb) ----
#pragma unroll
    for (int r = 0; r < 8; ++r) {
      *(f16x4*)&As[r*16 + lrow][lcol] = cvt4(raA[r]);
      *(f16x4*)&Bs[r*16 + lrow][lcol] = cvt4(rb[r]);
    }
    if ((k0 >> 7) == ct) {   // qry passthrough for cols [k0, k0+64)
#pragma unroll
      for (int r = 0; r < 8; ++r)
        *(float4*)&oq[(size_t)(r*16 + lrow) * ND + k0 + lcol] = rb[r];
    }
    __syncthreads();
    loadQ(k0 + 64);                          // depth-1 (always valid)
    if (k0 + 128 < ND) loadCtx(k0 + 128, raA); // depth-2
    mfmaPhase();
    __syncthreads();
    // ---- substep B: tile k0+64 (ctx from raB, qry from rb) ----
#pragma unroll
    for (int r = 0; r < 8; ++r) {
      *(f16x4*)&As[r*16 + lrow][lcol] = cvt4(raB[r]);
      *(f16x4*)&Bs[r*16 + lrow][lcol] = cvt4(rb[r]);
    }
    if ((k0 >> 7) == ct) {   // qry passthrough for cols [k0+64, k0+128)
#pragma unroll
      for (int r = 0; r < 8; ++r)
        *(float4*)&oq[(size_t)(r*16 + lrow) * ND + k0 + 64 + lcol] = rb[r];
    }
    __syncthreads();
    if (k0 + 128 < ND) loadQ(k0 + 128);
    if (k0 + 192 < ND) loadCtx(k0 + 192, raB);
    mfmaPhase();
    __syncthreads();
  }

  // leaky-relu + sum of squares over q (cols) for each c row
#pragma unroll
  for (int m = 0; m < 4; ++m) {
#pragma unroll
    for (int i = 0; i < 4; ++i) {
      float ss = 0.f;
#pragma unroll
      for (int n = 0; n < 4; ++n) {
        float v = acc[m][n][i];
        v = v > 0.f ? v : 0.1f * v;
        acc[m][n][i] = v;
        ss += v * v;
      }
      ss += __shfl_xor(ss, 1);
      ss += __shfl_xor(ss, 2);
      ss += __shfl_xor(ss, 4);
      ss += __shfl_xor(ss, 8);
      if (l15 == 0) nrm[wn][wm*64 + m*16 + g*4 + i] = ss;
    }
  }
  __syncthreads();

  // scale -> logit -> exp (fp16 store) + per-q column-sum partials
  const float LOG2E = 1.4426950408889634f;
  _Float16* Eb = Ew + (size_t)b * NQ * NC;
  float sE[4] = {0.f, 0.f, 0.f, 0.f};
#pragma unroll
  for (int m = 0; m < 4; ++m) {
    const int crow = wm*64 + m*16 + g*4;
    float sc[4];
#pragma unroll
    for (int i = 0; i < 4; ++i) {
      float nn = nrm[0][crow + i] + nrm[1][crow + i];
      sc[i] = 9.0f / (sqrtf(nn) + 1e-8f);
    }
#pragma unroll
    for (int n = 0; n < 4; ++n) {
      const int qq = wn*64 + n*16 + l15;
      f16x4 h;
#pragma unroll
      for (int i = 0; i < 4; ++i) {
        float e = exp2f(acc[m][n][i] * sc[i] * LOG2E);
        h[i] = (_Float16)e;
        sE[n] += e;
      }
      *(f16x4*)&Eb[(size_t)qq * NC + c0 + crow] = h;
    }
  }
  // reduce colsums across g (lane bits 4,5), then across wm via LDS
#pragma unroll
  for (int n = 0; n < 4; ++n) {
    sE[n] += __shfl_xor(sE[n], 16);
    sE[n] += __shfl_xor(sE[n], 32);
  }
  if (g == 0) {
#pragma unroll
    for (int n = 0; n < 4; ++n) sps[wm][wn*64 + n*16 + l15] = sE[n];
  }
  __syncthreads();
  if (wm == 0 && g == 0) {
#pragma unroll
    for (int n = 0; n < 4; ++n) {
      const int q64 = wn*64 + n*16 + l15;
      psw[((size_t)b * NQ + q64) * 8 + ct] = sps[0][q64] + sps[1][q64];
    }
  }
}

// ---------------------------------------------------------------------------
// K2: P[b][q][c] = E[b][q][c] / sum_c E  (fp32 to out_a). Pure scale pass.
// ---------------------------------------------------------------------------
__global__ __launch_bounds__(256) void k2_scale(
    const _Float16* __restrict__ Ew, const float* __restrict__ psw,
    float* __restrict__ pout)
{
  const int row  = blockIdx.x * 4 + (threadIdx.x >> 6);
  const int lane = threadIdx.x & 63;

  float s = 0.f;
#pragma unroll
  for (int j = 0; j < 8; ++j) s += psw[(size_t)row * 8 + j];
  const float r = 1.0f / s;

  const _Float16* e = Ew + (size_t)row * NC;
  float* p = pout + (size_t)row * NC;
#pragma unroll
  for (int hseg = 0; hseg < 2; ++hseg) {
    f16x8 v = *(const f16x8*)&e[lane * 8 + hseg * 512];
    float4 lo, hi;
    lo.x = (float)v[0] * r;  lo.y = (float)v[1] * r;
    lo.z = (float)v[2] * r;  lo.w = (float)v[3] * r;
    hi.x = (float)v[4] * r;  hi.y = (float)v[5] * r;
    hi.z = (float)v[6] * r;  hi.w = (float)v[7] * r;
    *(float4*)&p[lane * 8 + hseg * 512]     = lo;
    *(float4*)&p[lane * 8 + hseg * 512 + 4] = hi;
  }
}

// ---------------------------------------------------------------------------
// K3: wcontext[b][q][d] = sum_c P[b][q][c] * ctx[b][c][d]
// A = P rows (L3-hot, depth-1); B = ctx^T reg-transposed (HBM-cold, depth-2
// ping-pong rcA/rcB). Overwrites the E/ps scratch with W.
// ---------------------------------------------------------------------------
__global__ __launch_bounds__(256, 2) void k3_wctx(
    const float* __restrict__ attn, const float* __restrict__ ctx,
    float* __restrict__ wout)
{
  __shared__ _Float16 Ps[128][72];   // P rows (q), k=c contiguous
  __shared__ _Float16 Cs[128][68];   // ctx^T rows (d), k=c contiguous

  int b, dt;
  remap(b, dt);
  const int d0 = dt * 128;
  const int t  = threadIdx.x;
  const int lane = t & 63, wave = t >> 6;
  const int wm = wave >> 1, wn = wave & 1;
  const int g = lane >> 4, l15 = lane & 15;
  const int lrow = t >> 4, lcol = (t & 15) * 4;
  const int d4 = t & 31;      // d quad (0..31)
  const int cq0 = t >> 5;     // c quad base (0..7)

  const float* ctxB = ctx + (size_t)b * NC * ND;
  const float* pB   = attn + (size_t)b * NQ * NC;

  f32x4 acc[4][4] = {};
  float4 pa[8], rcA[8], rcB[8];

  auto loadP = [&](int k0) {
#pragma unroll
    for (int r = 0; r < 8; ++r)
      pa[r] = *(const float4*)&pB[(size_t)(r*16 + lrow) * NC + k0 + lcol];
  };
  auto loadCtx = [&](int k0, float4 (&rc)[8]) {
#pragma unroll
    for (int p = 0; p < 2; ++p) {
      const int cc = (cq0 + p*8) * 4;
#pragma unroll
      for (int j = 0; j < 4; ++j)
        rc[p*4 + j] = *(const float4*)&ctxB[(size_t)(k0 + cc + j) * ND + d0 + d4*4];
    }
  };
  auto writeCs = [&](float4 (&rc)[8]) {
#pragma unroll
    for (int p = 0; p < 2; ++p) {
      const int cc = (cq0 + p*8) * 4;
      float4 r0 = rc[p*4+0], r1 = rc[p*4+1], r2 = rc[p*4+2], r3 = rc[p*4+3];
      *(f16x4*)&Cs[d4*4 + 0][cc] = cvtT(r0.x, r1.x, r2.x, r3.x);
      *(f16x4*)&Cs[d4*4 + 1][cc] = cvtT(r0.y, r1.y, r2.y, r3.y);
      *(f16x4*)&Cs[d4*4 + 2][cc] = cvtT(r0.z, r1.z, r2.z, r3.z);
      *(f16x4*)&Cs[d4*4 + 3][cc] = cvtT(r0.w, r1.w, r2.w, r3.w);
    }
  };
  auto mfmaPhase = [&]() {
#pragma unroll
    for (int kk = 0; kk < 2; ++kk) {
      f16x8 af[4], bf[4];
#pragma unroll
      for (int m = 0; m < 4; ++m)
        af[m] = *(const f16x8*)&Ps[wm*64 + m*16 + l15][kk*32 + g*8];
#pragma unroll
      for (int n = 0; n < 4; ++n) {
        const int rowd = wn*64 + n*16 + l15;
        f16x4 blo = *(const f16x4*)&Cs[rowd][kk*32 + g*8];
        f16x4 bhi = *(const f16x4*)&Cs[rowd][kk*32 + g*8 + 4];
        bf[n] = (f16x8){blo[0], blo[1], blo[2], blo[3],
                        bhi[0], bhi[1], bhi[2], bhi[3]};
      }
#pragma unroll
      for (int m = 0; m < 4; ++m)
#pragma unroll
        for (int n = 0; n < 4; ++n)
          acc[m][n] = __builtin_amdgcn_mfma_f32_16x16x32_f16(af[m], bf[n], acc[m][n], 0, 0, 0);
    }
  };

  loadP(0);
  loadCtx(0, rcA);
  loadCtx(64, rcB);

  for (int k0 = 0; k0 < NC; k0 += 128) {
    // ---- substep A: tile k0 ----
#pragma unroll
    for (int r = 0; r < 8; ++r)
      *(f16x4*)&Ps[r*16 + lrow][lcol] = cvt4(pa[r]);
    writeCs(rcA);
    __syncthreads();
    loadP(k0 + 64);                            // depth-1
    if (k0 + 128 < NC) loadCtx(k0 + 128, rcA); // depth-2
    mfmaPhase();
    __syncthreads();
    // ---- substep B: tile k0+64 ----
#pragma unroll
    for (int r = 0; r < 8; ++r)
      *(f16x4*)&Ps[r*16 + lrow][lcol] = cvt4(pa[r]);
    writeCs(rcB);
    __syncthreads();
    if (k0 + 128 < NC) loadP(k0 + 128);
    if (k0 + 192 < NC) loadCtx(k0 + 192, rcB);
    mfmaPhase();
    __syncthreads();
  }

  float* wB = wout + (size_t)b * NQ * ND;
#pragma unroll
  for (int m = 0; m < 4; ++m) {
    const int qrow = wm*64 + m*16 + g*4;
#pragma unroll
    for (int n = 0; n < 4; ++n) {
      const int dd = d0 + wn*64 + n*16 + l15;
#pragma unroll
      for (int i = 0; i < 4; ++i)
        wB[(size_t)(qrow + i) * ND + dd] = acc[m][n][i];
    }
  }
}

// ---------------------------------------------------------------------------
extern "C" void kernel_launch(void* const* d_in, const int* in_sizes, int n_in,
                              void* d_out, int out_size, void* d_ws, size_t ws_size,
                              hipStream_t stream)
{
  const float* qry = (const float*)d_in[0];
  const float* ctx = (const float*)d_in[1];
  float* out   = (float*)d_out;
  float* out_q = out;                                  // query passthrough
  float* out_w = out + (size_t)NB * NQ * ND;           // wcontext (scratch first)
  float* out_a = out + 2 * (size_t)NB * NQ * ND;       // attn (P)

  // Scratch inside out_w (dead until K3's epilogue overwrites it with W):
  //   E  fp16, NB*NQ*NC halves = 32 MiB;  ps fp32 512 KiB after it.
  _Float16* Ew = (_Float16*)out_w;
  float* psw = out_w + (size_t)NB * NQ * NC / 2;

  k1_logits_exp<<<dim3(8, 128), 256, 0, stream>>>(qry, ctx, Ew, psw, out_q);
  k2_scale<<<dim3(4096), 256, 0, stream>>>(Ew, psw, out_a);
  k3_wctx<<<dim3(8, 128), 256, 0, stream>>>(out_a, ctx, out_w);
}

// Round 9
// 294.949 us; speedup vs baseline: 1.3264x; 1.3264x over previous
//
#include <hip/hip_runtime.h>
#include <math.h>

typedef __attribute__((ext_vector_type(4))) float f32x4;
typedef __attribute__((ext_vector_type(8))) _Float16 f16x8;
typedef __attribute__((ext_vector_type(4))) _Float16 f16x4;

#define NB 128
#define NQ 128
#define NC 1024
#define ND 1024

static __device__ __forceinline__ f16x4 cvt4(float4 v) {
  auto lo = __builtin_amdgcn_cvt_pkrtz(v.x, v.y);   // __fp16 ext_vector(2)
  auto hi = __builtin_amdgcn_cvt_pkrtz(v.z, v.w);
  return (f16x4){(_Float16)lo[0], (_Float16)lo[1],
                 (_Float16)hi[0], (_Float16)hi[1]};
}
static __device__ __forceinline__ f16x4 cvtT(float a, float b, float c, float d) {
  auto lo = __builtin_amdgcn_cvt_pkrtz(a, b);
  auto hi = __builtin_amdgcn_cvt_pkrtz(c, d);
  return (f16x4){(_Float16)lo[0], (_Float16)lo[1],
                 (_Float16)hi[0], (_Float16)hi[1]};
}

// XCD-grouping remap: linear L = x + 8*y, XCD = L%8 (8 XCDs, round-robin).
// b = (L&7) + 8*(L>>6), tile = (L>>3)&7  ->  all 8 tile-blocks of a given b
// are L≡b (mod 8): same XCD, adjacent in dispatch -> qry[b]/E[b] L2-shared.
static __device__ __forceinline__ void remap(int& b, int& tile) {
  const int L = blockIdx.x + ((int)gridDim.x) * blockIdx.y;
  b = (L & 7) + 8 * (L >> 6);
  tile = (L >> 3) & 7;
}

// ---------------------------------------------------------------------------
// K1: E[b][q][c] = exp(9*lrelu(S)/(||lrelu(S)||_q + 1e-8))  (fp16)
//     ps[b][q][ct] = sum_{c in tile} E  (per-tile partials, deterministic)
//     S[c][q] = sum_d ctx[b][c][d]*qry[b][q][d]
// Logits bounded in [-9,9] -> exp without max-subtraction is safe.
// Also copies its d-slice of qry[b] to out_q from the staging registers.
// (R6-proven structure: depth-1 combined prefetch, 2 barriers per BK=64.)
// ---------------------------------------------------------------------------
__global__ __launch_bounds__(256, 2) void k1_logits_exp(
    const float* __restrict__ qry, const float* __restrict__ ctx,
    _Float16* __restrict__ Ew, float* __restrict__ psw,
    float* __restrict__ outq)
{
  __shared__ _Float16 As[128][72];   // context rows (c), k contiguous
  __shared__ _Float16 Bs[128][72];   // query rows (q)
  __shared__ float nrm[2][128];      // per-c-row sumsq partials (by wn)
  __shared__ float sps[2][128];      // per-q colsum partials (by wm)

  int b, ct;
  remap(b, ct);
  const int c0 = ct * 128;
  const int t  = threadIdx.x;
  const int lane = t & 63, wave = t >> 6;
  const int wm = wave >> 1, wn = wave & 1;
  const int g = lane >> 4, l15 = lane & 15;
  const int lrow = t >> 4, lcol = (t & 15) * 4;

  const float* ctxB = ctx + (size_t)b * NC * ND;
  const float* qB   = qry + (size_t)b * NQ * ND;

  f32x4 acc[4][4] = {};
  float4 ra[8], rb[8];

  auto k1_load = [&](int k0) {
#pragma unroll
    for (int r = 0; r < 8; ++r) {
      ra[r] = *(const float4*)&ctxB[(size_t)(c0 + r*16 + lrow) * ND + k0 + lcol];
      rb[r] = *(const float4*)&qB[(size_t)(r*16 + lrow) * ND + k0 + lcol];
    }
  };

  k1_load(0);
  for (int k0 = 0; k0 < ND; k0 += 64) {
#pragma unroll
    for (int r = 0; r < 8; ++r) {
      *(f16x4*)&As[r*16 + lrow][lcol] = cvt4(ra[r]);
      *(f16x4*)&Bs[r*16 + lrow][lcol] = cvt4(rb[r]);
    }
    // qry passthrough: this block owns d-columns [128ct, 128ct+128)
    if ((k0 >> 7) == ct) {
      float* oq = outq + (size_t)b * NQ * ND;
#pragma unroll
      for (int r = 0; r < 8; ++r)
        *(float4*)&oq[(size_t)(r*16 + lrow) * ND + k0 + lcol] = rb[r];
    }
    __syncthreads();
    if (k0 + 64 < ND) k1_load(k0 + 64);   // prefetch overlaps MFMA below
#pragma unroll
    for (int kk = 0; kk < 2; ++kk) {
      f16x8 af[4], bf[4];
#pragma unroll
      for (int m = 0; m < 4; ++m)
        af[m] = *(const f16x8*)&As[wm*64 + m*16 + l15][kk*32 + g*8];
#pragma unroll
      for (int n = 0; n < 4; ++n)
        bf[n] = *(const f16x8*)&Bs[wn*64 + n*16 + l15][kk*32 + g*8];
#pragma unroll
      for (int m = 0; m < 4; ++m)
#pragma unroll
        for (int n = 0; n < 4; ++n)
          acc[m][n] = __builtin_amdgcn_mfma_f32_16x16x32_f16(af[m], bf[n], acc[m][n], 0, 0, 0);
    }
    __syncthreads();
  }

  // leaky-relu + sum of squares over q (cols) for each c row
#pragma unroll
  for (int m = 0; m < 4; ++m) {
#pragma unroll
    for (int i = 0; i < 4; ++i) {
      float ss = 0.f;
#pragma unroll
      for (int n = 0; n < 4; ++n) {
        float v = acc[m][n][i];
        v = v > 0.f ? v : 0.1f * v;
        acc[m][n][i] = v;
        ss += v * v;
      }
      ss += __shfl_xor(ss, 1);
      ss += __shfl_xor(ss, 2);
      ss += __shfl_xor(ss, 4);
      ss += __shfl_xor(ss, 8);
      if (l15 == 0) nrm[wn][wm*64 + m*16 + g*4 + i] = ss;
    }
  }
  __syncthreads();

  // scale -> logit -> exp (fp16 store) + per-q column-sum partials
  const float LOG2E = 1.4426950408889634f;
  _Float16* Eb = Ew + (size_t)b * NQ * NC;
  float sE[4] = {0.f, 0.f, 0.f, 0.f};
#pragma unroll
  for (int m = 0; m < 4; ++m) {
    const int crow = wm*64 + m*16 + g*4;
    float sc[4];
#pragma unroll
    for (int i = 0; i < 4; ++i) {
      float nn = nrm[0][crow + i] + nrm[1][crow + i];
      sc[i] = 9.0f / (sqrtf(nn) + 1e-8f);
    }
#pragma unroll
    for (int n = 0; n < 4; ++n) {
      const int qq = wn*64 + n*16 + l15;
      f16x4 h;
#pragma unroll
      for (int i = 0; i < 4; ++i) {
        float e = exp2f(acc[m][n][i] * sc[i] * LOG2E);
        h[i] = (_Float16)e;
        sE[n] += e;
      }
      *(f16x4*)&Eb[(size_t)qq * NC + c0 + crow] = h;
    }
  }
  // reduce colsums across g (lane bits 4,5), then across wm via LDS
#pragma unroll
  for (int n = 0; n < 4; ++n) {
    sE[n] += __shfl_xor(sE[n], 16);
    sE[n] += __shfl_xor(sE[n], 32);
  }
  if (g == 0) {
#pragma unroll
    for (int n = 0; n < 4; ++n) sps[wm][wn*64 + n*16 + l15] = sE[n];
  }
  __syncthreads();
  if (wm == 0 && g == 0) {
#pragma unroll
    for (int n = 0; n < 4; ++n) {
      const int q64 = wn*64 + n*16 + l15;
      psw[((size_t)b * NQ + q64) * 8 + ct] = sps[0][q64] + sps[1][q64];
    }
  }
}

// ---------------------------------------------------------------------------
// K2: P[b][q][c] = E[b][q][c] / sum_c E  (fp32 to out_a). Pure scale pass.
// ---------------------------------------------------------------------------
__global__ __launch_bounds__(256) void k2_scale(
    const _Float16* __restrict__ Ew, const float* __restrict__ psw,
    float* __restrict__ pout)
{
  const int row  = blockIdx.x * 4 + (threadIdx.x >> 6);
  const int lane = threadIdx.x & 63;

  float s = 0.f;
#pragma unroll
  for (int j = 0; j < 8; ++j) s += psw[(size_t)row * 8 + j];
  const float r = 1.0f / s;

  const _Float16* e = Ew + (size_t)row * NC;
  float* p = pout + (size_t)row * NC;
#pragma unroll
  for (int hseg = 0; hseg < 2; ++hseg) {
    f16x8 v = *(const f16x8*)&e[lane * 8 + hseg * 512];
    float4 lo, hi;
    lo.x = (float)v[0] * r;  lo.y = (float)v[1] * r;
    lo.z = (float)v[2] * r;  lo.w = (float)v[3] * r;
    hi.x = (float)v[4] * r;  hi.y = (float)v[5] * r;
    hi.z = (float)v[6] * r;  hi.w = (float)v[7] * r;
    *(float4*)&p[lane * 8 + hseg * 512]     = lo;
    *(float4*)&p[lane * 8 + hseg * 512 + 4] = hi;
  }
}

// ---------------------------------------------------------------------------
// K3e: wcontext[b][q][d] = rsu[q] * sum_c E[b][q][c] * ctx[b][c][d]
// A = E fp16 rows straight from ws (no cvt, 4 coalesced 16B loads/thread);
// B = ctx^T via reg transpose; accumulator scaled by rsu in the epilogue.
// Processes b in REVERSE order so its first ctx reads hit the L3 tail that
// K1 just streamed. Independent of K2 (reads E/ps, not P).
// ---------------------------------------------------------------------------
__global__ __launch_bounds__(256, 2) void k3_wctx_e(
    const _Float16* __restrict__ Ew, const float* __restrict__ psw,
    const float* __restrict__ ctx, float* __restrict__ wout)
{
  __shared__ _Float16 Ps[128][72];   // E rows (q), k=c contiguous
  __shared__ _Float16 Cs[128][68];   // ctx^T rows (d), k=c contiguous
  __shared__ float rsu[128];         // 1/sumE per q

  int b, dt;
  remap(b, dt);
  b = NB - 1 - b;            // reverse: ride K1's L3 tail of ctx
  const int d0 = dt * 128;
  const int t  = threadIdx.x;
  const int lane = t & 63, wave = t >> 6;
  const int wm = wave >> 1, wn = wave & 1;
  const int g = lane >> 4, l15 = lane & 15;
  const int d4 = t & 31;      // d quad (0..31)
  const int cq0 = t >> 5;     // c quad base (0..7)
  const int rE = t >> 3;      // E-staging row (0..31, x4 passes)
  const int cE = (t & 7) * 8; // E-staging col base

  const float* ctxB = ctx + (size_t)b * NC * ND;
  const _Float16* Eb = Ew + (size_t)b * NQ * NC;

  if (t < 128) {
    const float* pp = &psw[((size_t)b * NQ + t) * 8];
    float4 a = *(const float4*)pp;
    float4 c4 = *(const float4*)(pp + 4);
    rsu[t] = 1.0f / (a.x + a.y + a.z + a.w + c4.x + c4.y + c4.z + c4.w);
  }

  f32x4 acc[4][4] = {};
  f16x8 eh[4];
  float4 rc[8];

  auto loadE = [&](int k0) {
#pragma unroll
    for (int r = 0; r < 4; ++r)
      eh[r] = *(const f16x8*)&Eb[(size_t)(r*32 + rE) * NC + k0 + cE];
  };
  auto loadB = [&](int k0) {
#pragma unroll
    for (int p = 0; p < 2; ++p) {
      const int cc = (cq0 + p*8) * 4;
#pragma unroll
      for (int j = 0; j < 4; ++j)
        rc[p*4 + j] = *(const float4*)&ctxB[(size_t)(k0 + cc + j) * ND + d0 + d4*4];
    }
  };

  loadE(0);
  loadB(0);
  __syncthreads();   // rsu visible to all before first stage/epilogue

  for (int k0 = 0; k0 < NC; k0 += 64) {
    // write phase
#pragma unroll
    for (int r = 0; r < 4; ++r)
      *(f16x8*)&Ps[r*32 + rE][cE] = eh[r];
#pragma unroll
    for (int p = 0; p < 2; ++p) {
      const int cc = (cq0 + p*8) * 4;
      float4 r0 = rc[p*4+0], r1 = rc[p*4+1], r2 = rc[p*4+2], r3 = rc[p*4+3];
      *(f16x4*)&Cs[d4*4 + 0][cc] = cvtT(r0.x, r1.x, r2.x, r3.x);
      *(f16x4*)&Cs[d4*4 + 1][cc] = cvtT(r0.y, r1.y, r2.y, r3.y);
      *(f16x4*)&Cs[d4*4 + 2][cc] = cvtT(r0.z, r1.z, r2.z, r3.z);
      *(f16x4*)&Cs[d4*4 + 3][cc] = cvtT(r0.w, r1.w, r2.w, r3.w);
    }
    __syncthreads();
    if (k0 + 64 < NC) { loadE(k0 + 64); loadB(k0 + 64); }
#pragma unroll
    for (int kk = 0; kk < 2; ++kk) {
      f16x8 af[4], bf[4];
#pragma unroll
      for (int m = 0; m < 4; ++m)
        af[m] = *(const f16x8*)&Ps[wm*64 + m*16 + l15][kk*32 + g*8];
#pragma unroll
      for (int n = 0; n < 4; ++n) {
        const int rowd = wn*64 + n*16 + l15;
        f16x4 blo = *(const f16x4*)&Cs[rowd][kk*32 + g*8];
        f16x4 bhi = *(const f16x4*)&Cs[rowd][kk*32 + g*8 + 4];
        bf[n] = (f16x8){blo[0], blo[1], blo[2], blo[3],
                        bhi[0], bhi[1], bhi[2], bhi[3]};
      }
#pragma unroll
      for (int m = 0; m < 4; ++m)
#pragma unroll
        for (int n = 0; n < 4; ++n)
          acc[m][n] = __builtin_amdgcn_mfma_f32_16x16x32_f16(af[m], bf[n], acc[m][n], 0, 0, 0);
    }
    __syncthreads();
  }

  float* wB = wout + (size_t)b * NQ * ND;
#pragma unroll
  for (int m = 0; m < 4; ++m) {
    const int qrow = wm*64 + m*16 + g*4;
#pragma unroll
    for (int n = 0; n < 4; ++n) {
      const int dd = d0 + wn*64 + n*16 + l15;
#pragma unroll
      for (int i = 0; i < 4; ++i)
        wB[(size_t)(qrow + i) * ND + dd] = acc[m][n][i] * rsu[qrow + i];
    }
  }
}

// ---------------------------------------------------------------------------
// K3p (fallback, R6-proven): W = P @ ctx with P fp32 from out_a.
// ---------------------------------------------------------------------------
__global__ __launch_bounds__(256, 2) void k3_wctx_p(
    const float* __restrict__ attn, const float* __restrict__ ctx,
    float* __restrict__ wout)
{
  __shared__ _Float16 Ps[128][72];
  __shared__ _Float16 Cs[128][68];

  int b, dt;
  remap(b, dt);
  const int d0 = dt * 128;
  const int t  = threadIdx.x;
  const int lane = t & 63, wave = t >> 6;
  const int wm = wave >> 1, wn = wave & 1;
  const int g = lane >> 4, l15 = lane & 15;
  const int lrow = t >> 4, lcol = (t & 15) * 4;
  const int d4 = t & 31;
  const int cq0 = t >> 5;

  const float* ctxB = ctx + (size_t)b * NC * ND;
  const float* pB   = attn + (size_t)b * NQ * NC;

  f32x4 acc[4][4] = {};
  float4 pa[8], rc[8];

  auto k3_load = [&](int k0) {
#pragma unroll
    for (int r = 0; r < 8; ++r)
      pa[r] = *(const float4*)&pB[(size_t)(r*16 + lrow) * NC + k0 + lcol];
#pragma unroll
    for (int p = 0; p < 2; ++p) {
      const int cc = (cq0 + p*8) * 4;
#pragma unroll
      for (int j = 0; j < 4; ++j)
        rc[p*4 + j] = *(const float4*)&ctxB[(size_t)(k0 + cc + j) * ND + d0 + d4*4];
    }
  };

  k3_load(0);
  for (int k0 = 0; k0 < NC; k0 += 64) {
#pragma unroll
    for (int r = 0; r < 8; ++r)
      *(f16x4*)&Ps[r*16 + lrow][lcol] = cvt4(pa[r]);
#pragma unroll
    for (int p = 0; p < 2; ++p) {
      const int cc = (cq0 + p*8) * 4;
      float4 r0 = rc[p*4+0], r1 = rc[p*4+1], r2 = rc[p*4+2], r3 = rc[p*4+3];
      *(f16x4*)&Cs[d4*4 + 0][cc] = cvtT(r0.x, r1.x, r2.x, r3.x);
      *(f16x4*)&Cs[d4*4 + 1][cc] = cvtT(r0.y, r1.y, r2.y, r3.y);
      *(f16x4*)&Cs[d4*4 + 2][cc] = cvtT(r0.z, r1.z, r2.z, r3.z);
      *(f16x4*)&Cs[d4*4 + 3][cc] = cvtT(r0.w, r1.w, r2.w, r3.w);
    }
    __syncthreads();
    if (k0 + 64 < NC) k3_load(k0 + 64);
#pragma unroll
    for (int kk = 0; kk < 2; ++kk) {
      f16x8 af[4], bf[4];
#pragma unroll
      for (int m = 0; m < 4; ++m)
        af[m] = *(const f16x8*)&Ps[wm*64 + m*16 + l15][kk*32 + g*8];
#pragma unroll
      for (int n = 0; n < 4; ++n) {
        const int rowd = wn*64 + n*16 + l15;
        f16x4 blo = *(const f16x4*)&Cs[rowd][kk*32 + g*8];
        f16x4 bhi = *(const f16x4*)&Cs[rowd][kk*32 + g*8 + 4];
        bf[n] = (f16x8){blo[0], blo[1], blo[2], blo[3],
                        bhi[0], bhi[1], bhi[2], bhi[3]};
      }
#pragma unroll
      for (int m = 0; m < 4; ++m)
#pragma unroll
        for (int n = 0; n < 4; ++n)
          acc[m][n] = __builtin_amdgcn_mfma_f32_16x16x32_f16(af[m], bf[n], acc[m][n], 0, 0, 0);
    }
    __syncthreads();
  }

  float* wB = wout + (size_t)b * NQ * ND;
#pragma unroll
  for (int m = 0; m < 4; ++m) {
    const int qrow = wm*64 + m*16 + g*4;
#pragma unroll
    for (int n = 0; n < 4; ++n) {
      const int dd = d0 + wn*64 + n*16 + l15;
#pragma unroll
      for (int i = 0; i < 4; ++i)
        wB[(size_t)(qrow + i) * ND + dd] = acc[m][n][i];
    }
  }
}

// ---------------------------------------------------------------------------
extern "C" void kernel_launch(void* const* d_in, const int* in_sizes, int n_in,
                              void* d_out, int out_size, void* d_ws, size_t ws_size,
                              hipStream_t stream)
{
  const float* qry = (const float*)d_in[0];
  const float* ctx = (const float*)d_in[1];
  float* out   = (float*)d_out;
  float* out_q = out;                                  // query passthrough
  float* out_w = out + (size_t)NB * NQ * ND;           // wcontext
  float* out_a = out + 2 * (size_t)NB * NQ * ND;       // attn (P)

  const size_t E_BYTES  = (size_t)NB * NQ * NC * sizeof(_Float16);   // 32 MiB
  const size_t PS_BYTES = (size_t)NB * NQ * 8 * sizeof(float);       // 512 KiB

  if (ws_size >= E_BYTES + PS_BYTES) {
    // E + ps in workspace: K3 reads E directly (no alias with its W writes).
    _Float16* Ew = (_Float16*)d_ws;
    float* psw = (float*)((char*)d_ws + E_BYTES);
    k1_logits_exp<<<dim3(8, 128), 256, 0, stream>>>(qry, ctx, Ew, psw, out_q);
    k2_scale<<<dim3(4096), 256, 0, stream>>>(Ew, psw, out_a);
    k3_wctx_e<<<dim3(8, 128), 256, 0, stream>>>(Ew, psw, ctx, out_w);
  } else {
    // R6 fallback: E/ps scratch inside out_w, K3 consumes fp32 P from out_a.
    _Float16* Ew = (_Float16*)out_w;
    float* psw = out_w + (size_t)NB * NQ * NC / 2;
    k1_logits_exp<<<dim3(8, 128), 256, 0, stream>>>(qry, ctx, Ew, psw, out_q);
    k2_scale<<<dim3(4096), 256, 0, stream>>>(Ew, psw, out_a);
    k3_wctx_p<<<dim3(8, 128), 256, 0, stream>>>(out_a, ctx, out_w);
  }
}

// Round 10
// 291.311 us; speedup vs baseline: 1.3430x; 1.0125x over previous
//
#include <hip/hip_runtime.h>
#include <math.h>

typedef __attribute__((ext_vector_type(4))) float f32x4;
typedef __attribute__((ext_vector_type(8))) _Float16 f16x8;
typedef __attribute__((ext_vector_type(4))) _Float16 f16x4;

#define NB 128
#define NQ 128
#define NC 1024
#define ND 1024

static __device__ __forceinline__ f16x4 cvt4(float4 v) {
  auto lo = __builtin_amdgcn_cvt_pkrtz(v.x, v.y);   // __fp16 ext_vector(2)
  auto hi = __builtin_amdgcn_cvt_pkrtz(v.z, v.w);
  return (f16x4){(_Float16)lo[0], (_Float16)lo[1],
                 (_Float16)hi[0], (_Float16)hi[1]};
}
static __device__ __forceinline__ f16x4 cvtT(float a, float b, float c, float d) {
  auto lo = __builtin_amdgcn_cvt_pkrtz(a, b);
  auto hi = __builtin_amdgcn_cvt_pkrtz(c, d);
  return (f16x4){(_Float16)lo[0], (_Float16)lo[1],
                 (_Float16)hi[0], (_Float16)hi[1]};
}

// Single-barrier boundary: ds-writes visible (lgkmcnt0) + raw s_barrier that
// does NOT drain vmcnt -> prefetch loads survive into the next k-step.
// sched_barrier(0) fences per rule #18 (compiler must not hoist across).
static __device__ __forceinline__ void pipe_barrier() {
  asm volatile("s_waitcnt lgkmcnt(0)" ::: "memory");
  __builtin_amdgcn_sched_barrier(0);
  __builtin_amdgcn_s_barrier();
  __builtin_amdgcn_sched_barrier(0);
}

// XCD-grouping remap: linear L = x + 8*y, XCD = L%8 (8 XCDs, round-robin).
// b = (L&7) + 8*(L>>6), tile = (L>>3)&7  ->  all 8 tile-blocks of a given b
// are L≡b (mod 8): same XCD, adjacent in dispatch -> qry[b]/E[b] L2-shared.
static __device__ __forceinline__ void remap(int& b, int& tile) {
  const int L = blockIdx.x + ((int)gridDim.x) * blockIdx.y;
  b = (L & 7) + 8 * (L >> 6);
  tile = (L >> 3) & 7;
}

// ---------------------------------------------------------------------------
// K1: E[b][q][c] = exp(9*lrelu(S)/(||lrelu(S)||_q + 1e-8))  (fp16)
//     ps[b][q][ct] = per-tile colsum partials.  S[c][q]=sum_d ctx[c][d]q[q][d]
// Double-buffered LDS, ONE raw barrier per BK=64 k-step (loads cross it).
// Logits bounded in [-9,9] -> exp without max-subtraction is safe.
// Also copies its d-slice of qry[b] to out_q from the staging registers.
// ---------------------------------------------------------------------------
__global__ __launch_bounds__(256, 2) void k1_logits_exp(
    const float* __restrict__ qry, const float* __restrict__ ctx,
    _Float16* __restrict__ Ew, float* __restrict__ psw,
    float* __restrict__ outq)
{
  __shared__ _Float16 As[2][128][72];  // context rows (c), k contiguous
  __shared__ _Float16 Bs[2][128][72];  // query rows (q)
  __shared__ float nrm[2][128];        // per-c-row sumsq partials (by wn)
  __shared__ float sps[2][128];        // per-q colsum partials (by wm)

  int b, ct;
  remap(b, ct);
  const int c0 = ct * 128;
  const int t  = threadIdx.x;
  const int lane = t & 63, wave = t >> 6;
  const int wm = wave >> 1, wn = wave & 1;
  const int g = lane >> 4, l15 = lane & 15;
  const int lrow = t >> 4, lcol = (t & 15) * 4;

  const float* ctxB = ctx + (size_t)b * NC * ND;
  const float* qB   = qry + (size_t)b * NQ * ND;

  f32x4 acc[4][4] = {};
  float4 ra[8], rb[8];

  auto k1_load = [&](int k0) {
#pragma unroll
    for (int r = 0; r < 8; ++r) {
      ra[r] = *(const float4*)&ctxB[(size_t)(c0 + r*16 + lrow) * ND + k0 + lcol];
      rb[r] = *(const float4*)&qB[(size_t)(r*16 + lrow) * ND + k0 + lcol];
    }
  };
  float* oq = outq + (size_t)b * NQ * ND;

  k1_load(0);
  for (int k0 = 0; k0 < ND; k0 += 64) {
    const int buf = (k0 >> 6) & 1;
    // write phase: cvt (compiler inserts fine vmcnt waits) + LDS store
#pragma unroll
    for (int r = 0; r < 8; ++r) {
      *(f16x4*)&As[buf][r*16 + lrow][lcol] = cvt4(ra[r]);
      *(f16x4*)&Bs[buf][r*16 + lrow][lcol] = cvt4(rb[r]);
    }
    // qry passthrough: this block owns d-columns [128ct, 128ct+128)
    if ((k0 >> 7) == ct) {
#pragma unroll
      for (int r = 0; r < 8; ++r)
        *(float4*)&oq[(size_t)(r*16 + lrow) * ND + k0 + lcol] = rb[r];
    }
    if (k0 + 64 < ND) k1_load(k0 + 64);   // in flight across the barrier
    pipe_barrier();
#pragma unroll
    for (int kk = 0; kk < 2; ++kk) {
      f16x8 af[4], bf[4];
#pragma unroll
      for (int m = 0; m < 4; ++m)
        af[m] = *(const f16x8*)&As[buf][wm*64 + m*16 + l15][kk*32 + g*8];
#pragma unroll
      for (int n = 0; n < 4; ++n)
        bf[n] = *(const f16x8*)&Bs[buf][wn*64 + n*16 + l15][kk*32 + g*8];
#pragma unroll
      for (int m = 0; m < 4; ++m)
#pragma unroll
        for (int n = 0; n < 4; ++n)
          acc[m][n] = __builtin_amdgcn_mfma_f32_16x16x32_f16(af[m], bf[n], acc[m][n], 0, 0, 0);
    }
    // no second barrier: next write targets buf^1
  }

  __syncthreads();   // all MFMA reads done before epilogue LDS reuse

  // leaky-relu + sum of squares over q (cols) for each c row
#pragma unroll
  for (int m = 0; m < 4; ++m) {
#pragma unroll
    for (int i = 0; i < 4; ++i) {
      float ss = 0.f;
#pragma unroll
      for (int n = 0; n < 4; ++n) {
        float v = acc[m][n][i];
        v = v > 0.f ? v : 0.1f * v;
        acc[m][n][i] = v;
        ss += v * v;
      }
      ss += __shfl_xor(ss, 1);
      ss += __shfl_xor(ss, 2);
      ss += __shfl_xor(ss, 4);
      ss += __shfl_xor(ss, 8);
      if (l15 == 0) nrm[wn][wm*64 + m*16 + g*4 + i] = ss;
    }
  }
  __syncthreads();

  // scale -> logit -> exp (fp16 store) + per-q column-sum partials
  const float LOG2E = 1.4426950408889634f;
  _Float16* Eb = Ew + (size_t)b * NQ * NC;
  float sE[4] = {0.f, 0.f, 0.f, 0.f};
#pragma unroll
  for (int m = 0; m < 4; ++m) {
    const int crow = wm*64 + m*16 + g*4;
    float sc[4];
#pragma unroll
    for (int i = 0; i < 4; ++i) {
      float nn = nrm[0][crow + i] + nrm[1][crow + i];
      sc[i] = 9.0f / (sqrtf(nn) + 1e-8f);
    }
#pragma unroll
    for (int n = 0; n < 4; ++n) {
      const int qq = wn*64 + n*16 + l15;
      f16x4 h;
#pragma unroll
      for (int i = 0; i < 4; ++i) {
        float e = exp2f(acc[m][n][i] * sc[i] * LOG2E);
        h[i] = (_Float16)e;
        sE[n] += e;
      }
      *(f16x4*)&Eb[(size_t)qq * NC + c0 + crow] = h;
    }
  }
  // reduce colsums across g (lane bits 4,5), then across wm via LDS
#pragma unroll
  for (int n = 0; n < 4; ++n) {
    sE[n] += __shfl_xor(sE[n], 16);
    sE[n] += __shfl_xor(sE[n], 32);
  }
  if (g == 0) {
#pragma unroll
    for (int n = 0; n < 4; ++n) sps[wm][wn*64 + n*16 + l15] = sE[n];
  }
  __syncthreads();
  if (wm == 0 && g == 0) {
#pragma unroll
    for (int n = 0; n < 4; ++n) {
      const int q64 = wn*64 + n*16 + l15;
      psw[((size_t)b * NQ + q64) * 8 + ct] = sps[0][q64] + sps[1][q64];
    }
  }
}

// ---------------------------------------------------------------------------
// K2: P[b][q][c] = E[b][q][c] / sum_c E  (fp32 to out_a). Pure scale pass.
// ---------------------------------------------------------------------------
__global__ __launch_bounds__(256) void k2_scale(
    const _Float16* __restrict__ Ew, const float* __restrict__ psw,
    float* __restrict__ pout)
{
  const int row  = blockIdx.x * 4 + (threadIdx.x >> 6);
  const int lane = threadIdx.x & 63;

  float s = 0.f;
#pragma unroll
  for (int j = 0; j < 8; ++j) s += psw[(size_t)row * 8 + j];
  const float r = 1.0f / s;

  const _Float16* e = Ew + (size_t)row * NC;
  float* p = pout + (size_t)row * NC;
#pragma unroll
  for (int hseg = 0; hseg < 2; ++hseg) {
    f16x8 v = *(const f16x8*)&e[lane * 8 + hseg * 512];
    float4 lo, hi;
    lo.x = (float)v[0] * r;  lo.y = (float)v[1] * r;
    lo.z = (float)v[2] * r;  lo.w = (float)v[3] * r;
    hi.x = (float)v[4] * r;  hi.y = (float)v[5] * r;
    hi.z = (float)v[6] * r;  hi.w = (float)v[7] * r;
    *(float4*)&p[lane * 8 + hseg * 512]     = lo;
    *(float4*)&p[lane * 8 + hseg * 512 + 4] = hi;
  }
}

// ---------------------------------------------------------------------------
// K3e: wcontext[b][q][d] = rsu[q] * sum_c E[b][q][c] * ctx[b][c][d]
// A = E fp16 rows straight from ws (no cvt); B = ctx^T via reg transpose.
// Double-buffered LDS, one raw barrier per k-step. Reverse-b for L3 tail.
// ---------------------------------------------------------------------------
__global__ __launch_bounds__(256, 2) void k3_wctx_e(
    const _Float16* __restrict__ Ew, const float* __restrict__ psw,
    const float* __restrict__ ctx, float* __restrict__ wout)
{
  __shared__ _Float16 Ps[2][128][72];  // E rows (q), k=c contiguous
  __shared__ _Float16 Cs[2][128][68];  // ctx^T rows (d), k=c contiguous
  __shared__ float rsu[128];           // 1/sumE per q

  int b, dt;
  remap(b, dt);
  b = NB - 1 - b;            // reverse: ride K1's L3 tail of ctx
  const int d0 = dt * 128;
  const int t  = threadIdx.x;
  const int lane = t & 63, wave = t >> 6;
  const int wm = wave >> 1, wn = wave & 1;
  const int g = lane >> 4, l15 = lane & 15;
  const int d4 = t & 31;      // d quad (0..31)
  const int cq0 = t >> 5;     // c quad base (0..7)
  const int rE = t >> 3;      // E-staging row (0..31, x4 passes)
  const int cE = (t & 7) * 8; // E-staging col base

  const float* ctxB = ctx + (size_t)b * NC * ND;
  const _Float16* Eb = Ew + (size_t)b * NQ * NC;

  if (t < 128) {
    const float* pp = &psw[((size_t)b * NQ + t) * 8];
    float4 a = *(const float4*)pp;
    float4 c4 = *(const float4*)(pp + 4);
    rsu[t] = 1.0f / (a.x + a.y + a.z + a.w + c4.x + c4.y + c4.z + c4.w);
  }
  // rsu is read only in the epilogue; every wave passes >=1 pipe_barrier
  // (which includes lgkmcnt(0)) before then.

  f32x4 acc[4][4] = {};
  f16x8 eh[4];
  float4 rc[8];

  auto loadE = [&](int k0) {
#pragma unroll
    for (int r = 0; r < 4; ++r)
      eh[r] = *(const f16x8*)&Eb[(size_t)(r*32 + rE) * NC + k0 + cE];
  };
  auto loadB = [&](int k0) {
#pragma unroll
    for (int p = 0; p < 2; ++p) {
      const int cc = (cq0 + p*8) * 4;
#pragma unroll
      for (int j = 0; j < 4; ++j)
        rc[p*4 + j] = *(const float4*)&ctxB[(size_t)(k0 + cc + j) * ND + d0 + d4*4];
    }
  };

  loadE(0);
  loadB(0);

  for (int k0 = 0; k0 < NC; k0 += 64) {
    const int buf = (k0 >> 6) & 1;
    // write phase
#pragma unroll
    for (int r = 0; r < 4; ++r)
      *(f16x8*)&Ps[buf][r*32 + rE][cE] = eh[r];
#pragma unroll
    for (int p = 0; p < 2; ++p) {
      const int cc = (cq0 + p*8) * 4;
      float4 r0 = rc[p*4+0], r1 = rc[p*4+1], r2 = rc[p*4+2], r3 = rc[p*4+3];
      *(f16x4*)&Cs[buf][d4*4 + 0][cc] = cvtT(r0.x, r1.x, r2.x, r3.x);
      *(f16x4*)&Cs[buf][d4*4 + 1][cc] = cvtT(r0.y, r1.y, r2.y, r3.y);
      *(f16x4*)&Cs[buf][d4*4 + 2][cc] = cvtT(r0.z, r1.z, r2.z, r3.z);
      *(f16x4*)&Cs[buf][d4*4 + 3][cc] = cvtT(r0.w, r1.w, r2.w, r3.w);
    }
    if (k0 + 64 < NC) { loadE(k0 + 64); loadB(k0 + 64); }  // cross barrier
    pipe_barrier();
#pragma unroll
    for (int kk = 0; kk < 2; ++kk) {
      f16x8 af[4], bf[4];
#pragma unroll
      for (int m = 0; m < 4; ++m)
        af[m] = *(const f16x8*)&Ps[buf][wm*64 + m*16 + l15][kk*32 + g*8];
#pragma unroll
      for (int n = 0; n < 4; ++n) {
        const int rowd = wn*64 + n*16 + l15;
        f16x4 blo = *(const f16x4*)&Cs[buf][rowd][kk*32 + g*8];
        f16x4 bhi = *(const f16x4*)&Cs[buf][rowd][kk*32 + g*8 + 4];
        bf[n] = (f16x8){blo[0], blo[1], blo[2], blo[3],
                        bhi[0], bhi[1], bhi[2], bhi[3]};
      }
#pragma unroll
      for (int m = 0; m < 4; ++m)
#pragma unroll
        for (int n = 0; n < 4; ++n)
          acc[m][n] = __builtin_amdgcn_mfma_f32_16x16x32_f16(af[m], bf[n], acc[m][n], 0, 0, 0);
    }
  }

  float* wB = wout + (size_t)b * NQ * ND;
#pragma unroll
  for (int m = 0; m < 4; ++m) {
    const int qrow = wm*64 + m*16 + g*4;
#pragma unroll
    for (int n = 0; n < 4; ++n) {
      const int dd = d0 + wn*64 + n*16 + l15;
#pragma unroll
      for (int i = 0; i < 4; ++i)
        wB[(size_t)(qrow + i) * ND + dd] = acc[m][n][i] * rsu[qrow + i];
    }
  }
}

// ---------------------------------------------------------------------------
// K3p (fallback, R6-proven): W = P @ ctx with P fp32 from out_a. (Only used
// if ws is too small for E; evidence says ws ~= 2 GiB, so normally dead.)
// ---------------------------------------------------------------------------
__global__ __launch_bounds__(256, 2) void k3_wctx_p(
    const float* __restrict__ attn, const float* __restrict__ ctx,
    float* __restrict__ wout)
{
  __shared__ _Float16 Ps[128][72];
  __shared__ _Float16 Cs[128][68];

  int b, dt;
  remap(b, dt);
  const int d0 = dt * 128;
  const int t  = threadIdx.x;
  const int lane = t & 63, wave = t >> 6;
  const int wm = wave >> 1, wn = wave & 1;
  const int g = lane >> 4, l15 = lane & 15;
  const int lrow = t >> 4, lcol = (t & 15) * 4;
  const int d4 = t & 31;
  const int cq0 = t >> 5;

  const float* ctxB = ctx + (size_t)b * NC * ND;
  const float* pB   = attn + (size_t)b * NQ * NC;

  f32x4 acc[4][4] = {};
  float4 pa[8], rc[8];

  auto k3_load = [&](int k0) {
#pragma unroll
    for (int r = 0; r < 8; ++r)
      pa[r] = *(const float4*)&pB[(size_t)(r*16 + lrow) * NC + k0 + lcol];
#pragma unroll
    for (int p = 0; p < 2; ++p) {
      const int cc = (cq0 + p*8) * 4;
#pragma unroll
      for (int j = 0; j < 4; ++j)
        rc[p*4 + j] = *(const float4*)&ctxB[(size_t)(k0 + cc + j) * ND + d0 + d4*4];
    }
  };

  k3_load(0);
  for (int k0 = 0; k0 < NC; k0 += 64) {
#pragma unroll
    for (int r = 0; r < 8; ++r)
      *(f16x4*)&Ps[r*16 + lrow][lcol] = cvt4(pa[r]);
#pragma unroll
    for (int p = 0; p < 2; ++p) {
      const int cc = (cq0 + p*8) * 4;
      float4 r0 = rc[p*4+0], r1 = rc[p*4+1], r2 = rc[p*4+2], r3 = rc[p*4+3];
      *(f16x4*)&Cs[d4*4 + 0][cc] = cvtT(r0.x, r1.x, r2.x, r3.x);
      *(f16x4*)&Cs[d4*4 + 1][cc] = cvtT(r0.y, r1.y, r2.y, r3.y);
      *(f16x4*)&Cs[d4*4 + 2][cc] = cvtT(r0.z, r1.z, r2.z, r3.z);
      *(f16x4*)&Cs[d4*4 + 3][cc] = cvtT(r0.w, r1.w, r2.w, r3.w);
    }
    __syncthreads();
    if (k0 + 64 < NC) k3_load(k0 + 64);
#pragma unroll
    for (int kk = 0; kk < 2; ++kk) {
      f16x8 af[4], bf[4];
#pragma unroll
      for (int m = 0; m < 4; ++m)
        af[m] = *(const f16x8*)&Ps[wm*64 + m*16 + l15][kk*32 + g*8];
#pragma unroll
      for (int n = 0; n < 4; ++n) {
        const int rowd = wn*64 + n*16 + l15;
        f16x4 blo = *(const f16x4*)&Cs[rowd][kk*32 + g*8];
        f16x4 bhi = *(const f16x4*)&Cs[rowd][kk*32 + g*8 + 4];
        bf[n] = (f16x8){blo[0], blo[1], blo[2], blo[3],
                        bhi[0], bhi[1], bhi[2], bhi[3]};
      }
#pragma unroll
      for (int m = 0; m < 4; ++m)
#pragma unroll
        for (int n = 0; n < 4; ++n)
          acc[m][n] = __builtin_amdgcn_mfma_f32_16x16x32_f16(af[m], bf[n], acc[m][n], 0, 0, 0);
    }
    __syncthreads();
  }

  float* wB = wout + (size_t)b * NQ * ND;
#pragma unroll
  for (int m = 0; m < 4; ++m) {
    const int qrow = wm*64 + m*16 + g*4;
#pragma unroll
    for (int n = 0; n < 4; ++n) {
      const int dd = d0 + wn*64 + n*16 + l15;
#pragma unroll
      for (int i = 0; i < 4; ++i)
        wB[(size_t)(qrow + i) * ND + dd] = acc[m][n][i];
    }
  }
}

// ---------------------------------------------------------------------------
extern "C" void kernel_launch(void* const* d_in, const int* in_sizes, int n_in,
                              void* d_out, int out_size, void* d_ws, size_t ws_size,
                              hipStream_t stream)
{
  const float* qry = (const float*)d_in[0];
  const float* ctx = (const float*)d_in[1];
  float* out   = (float*)d_out;
  float* out_q = out;                                  // query passthrough
  float* out_w = out + (size_t)NB * NQ * ND;           // wcontext
  float* out_a = out + 2 * (size_t)NB * NQ * ND;       // attn (P)

  const size_t E_BYTES  = (size_t)NB * NQ * NC * sizeof(_Float16);   // 32 MiB
  const size_t PS_BYTES = (size_t)NB * NQ * 8 * sizeof(float);       // 512 KiB

  if (ws_size >= E_BYTES + PS_BYTES) {
    // E + ps in workspace: K3 reads E directly (no alias with its W writes).
    _Float16* Ew = (_Float16*)d_ws;
    float* psw = (float*)((char*)d_ws + E_BYTES);
    k1_logits_exp<<<dim3(8, 128), 256, 0, stream>>>(qry, ctx, Ew, psw, out_q);
    k2_scale<<<dim3(4096), 256, 0, stream>>>(Ew, psw, out_a);
    k3_wctx_e<<<dim3(8, 128), 256, 0, stream>>>(Ew, psw, ctx, out_w);
  } else {
    // R6 fallback: E/ps scratch inside out_w, K3 consumes fp32 P from out_a.
    _Float16* Ew = (_Float16*)out_w;
    float* psw = out_w + (size_t)NB * NQ * NC / 2;
    k1_logits_exp<<<dim3(8, 128), 256, 0, stream>>>(qry, ctx, Ew, psw, out_q);
    k2_scale<<<dim3(4096), 256, 0, stream>>>(Ew, psw, out_a);
    k3_wctx_p<<<dim3(8, 128), 256, 0, stream>>>(out_a, ctx, out_w);
  }
}

// Round 11
// 277.495 us; speedup vs baseline: 1.4098x; 1.0498x over previous
//
#include <hip/hip_runtime.h>
#include <math.h>

typedef __attribute__((ext_vector_type(4))) float f32x4;
typedef __attribute__((ext_vector_type(8))) _Float16 f16x8;
typedef __attribute__((ext_vector_type(4))) _Float16 f16x4;

#define NB 128
#define NQ 128
#define NC 1024
#define ND 1024

static __device__ __forceinline__ f16x4 cvt4(float4 v) {
  auto lo = __builtin_amdgcn_cvt_pkrtz(v.x, v.y);   // __fp16 ext_vector(2)
  auto hi = __builtin_amdgcn_cvt_pkrtz(v.z, v.w);
  return (f16x4){(_Float16)lo[0], (_Float16)lo[1],
                 (_Float16)hi[0], (_Float16)hi[1]};
}
static __device__ __forceinline__ f16x4 cvtT(float a, float b, float c, float d) {
  auto lo = __builtin_amdgcn_cvt_pkrtz(a, b);
  auto hi = __builtin_amdgcn_cvt_pkrtz(c, d);
  return (f16x4){(_Float16)lo[0], (_Float16)lo[1],
                 (_Float16)hi[0], (_Float16)hi[1]};
}

// Single-barrier boundary: ds-writes visible (lgkmcnt0) + raw s_barrier that
// does NOT drain vmcnt -> prefetch loads survive into the next k-step.
// sched_barrier(0) fences per rule #18 (compiler must not hoist across).
static __device__ __forceinline__ void pipe_barrier() {
  asm volatile("s_waitcnt lgkmcnt(0)" ::: "memory");
  __builtin_amdgcn_sched_barrier(0);
  __builtin_amdgcn_s_barrier();
  __builtin_amdgcn_sched_barrier(0);
}

// XCD-grouping remap: linear L = x + 8*y, XCD = L%8 (8 XCDs, round-robin).
// b = (L&7) + 8*(L>>6), tile = (L>>3)&7  ->  all 8 tile-blocks of a given b
// are L≡b (mod 8): same XCD, adjacent in dispatch -> qry[b]/E[b] L2-shared.
static __device__ __forceinline__ void remap(int& b, int& tile) {
  const int L = blockIdx.x + ((int)gridDim.x) * blockIdx.y;
  b = (L & 7) + 8 * (L >> 6);
  tile = (L >> 3) & 7;
}

// ---------------------------------------------------------------------------
// K1: E[b][q][c] = exp(9*lrelu(S)/(||lrelu(S)||_q + 1e-8))  (fp16)
//     ps[b][q][ct] = per-tile colsum partials.  S[c][q]=sum_d ctx[c][d]q[q][d]
// Double-buffered LDS, ONE raw barrier per BK=64 k-step (loads cross it).
// Logits bounded in [-9,9] -> exp without max-subtraction is safe.
// Also copies its d-slice of qry[b] to out_q from the staging registers.
// ---------------------------------------------------------------------------
__global__ __launch_bounds__(256, 2) void k1_logits_exp(
    const float* __restrict__ qry, const float* __restrict__ ctx,
    _Float16* __restrict__ Ew, float* __restrict__ psw,
    float* __restrict__ outq)
{
  __shared__ _Float16 As[2][128][72];  // context rows (c), k contiguous
  __shared__ _Float16 Bs[2][128][72];  // query rows (q)
  __shared__ float nrm[2][128];        // per-c-row sumsq partials (by wn)
  __shared__ float sps[2][128];        // per-q colsum partials (by wm)

  int b, ct;
  remap(b, ct);
  const int c0 = ct * 128;
  const int t  = threadIdx.x;
  const int lane = t & 63, wave = t >> 6;
  const int wm = wave >> 1, wn = wave & 1;
  const int g = lane >> 4, l15 = lane & 15;
  const int lrow = t >> 4, lcol = (t & 15) * 4;

  const float* ctxB = ctx + (size_t)b * NC * ND;
  const float* qB   = qry + (size_t)b * NQ * ND;

  f32x4 acc[4][4] = {};
  float4 ra[8], rb[8];

  auto k1_load = [&](int k0) {
#pragma unroll
    for (int r = 0; r < 8; ++r) {
      ra[r] = *(const float4*)&ctxB[(size_t)(c0 + r*16 + lrow) * ND + k0 + lcol];
      rb[r] = *(const float4*)&qB[(size_t)(r*16 + lrow) * ND + k0 + lcol];
    }
  };
  float* oq = outq + (size_t)b * NQ * ND;

  k1_load(0);
  for (int k0 = 0; k0 < ND; k0 += 64) {
    const int buf = (k0 >> 6) & 1;
    // write phase: cvt (compiler inserts fine vmcnt waits) + LDS store
#pragma unroll
    for (int r = 0; r < 8; ++r) {
      *(f16x4*)&As[buf][r*16 + lrow][lcol] = cvt4(ra[r]);
      *(f16x4*)&Bs[buf][r*16 + lrow][lcol] = cvt4(rb[r]);
    }
    // qry passthrough: this block owns d-columns [128ct, 128ct+128)
    if ((k0 >> 7) == ct) {
#pragma unroll
      for (int r = 0; r < 8; ++r)
        *(float4*)&oq[(size_t)(r*16 + lrow) * ND + k0 + lcol] = rb[r];
    }
    if (k0 + 64 < ND) k1_load(k0 + 64);   // in flight across the barrier
    pipe_barrier();
#pragma unroll
    for (int kk = 0; kk < 2; ++kk) {
      f16x8 af[4], bf[4];
#pragma unroll
      for (int m = 0; m < 4; ++m)
        af[m] = *(const f16x8*)&As[buf][wm*64 + m*16 + l15][kk*32 + g*8];
#pragma unroll
      for (int n = 0; n < 4; ++n)
        bf[n] = *(const f16x8*)&Bs[buf][wn*64 + n*16 + l15][kk*32 + g*8];
#pragma unroll
      for (int m = 0; m < 4; ++m)
#pragma unroll
        for (int n = 0; n < 4; ++n)
          acc[m][n] = __builtin_amdgcn_mfma_f32_16x16x32_f16(af[m], bf[n], acc[m][n], 0, 0, 0);
    }
    // no second barrier: next write targets buf^1
  }

  __syncthreads();   // all MFMA reads done before epilogue LDS reuse

  // leaky-relu + sum of squares over q (cols) for each c row
#pragma unroll
  for (int m = 0; m < 4; ++m) {
#pragma unroll
    for (int i = 0; i < 4; ++i) {
      float ss = 0.f;
#pragma unroll
      for (int n = 0; n < 4; ++n) {
        float v = acc[m][n][i];
        v = v > 0.f ? v : 0.1f * v;
        acc[m][n][i] = v;
        ss += v * v;
      }
      ss += __shfl_xor(ss, 1);
      ss += __shfl_xor(ss, 2);
      ss += __shfl_xor(ss, 4);
      ss += __shfl_xor(ss, 8);
      if (l15 == 0) nrm[wn][wm*64 + m*16 + g*4 + i] = ss;
    }
  }
  __syncthreads();

  // scale -> logit -> exp (fp16 store) + per-q column-sum partials
  const float LOG2E = 1.4426950408889634f;
  _Float16* Eb = Ew + (size_t)b * NQ * NC;
  float sE[4] = {0.f, 0.f, 0.f, 0.f};
#pragma unroll
  for (int m = 0; m < 4; ++m) {
    const int crow = wm*64 + m*16 + g*4;
    float sc[4];
#pragma unroll
    for (int i = 0; i < 4; ++i) {
      float nn = nrm[0][crow + i] + nrm[1][crow + i];
      sc[i] = 9.0f / (sqrtf(nn) + 1e-8f);
    }
#pragma unroll
    for (int n = 0; n < 4; ++n) {
      const int qq = wn*64 + n*16 + l15;
      f16x4 h;
#pragma unroll
      for (int i = 0; i < 4; ++i) {
        float e = exp2f(acc[m][n][i] * sc[i] * LOG2E);
        h[i] = (_Float16)e;
        sE[n] += e;
      }
      *(f16x4*)&Eb[(size_t)qq * NC + c0 + crow] = h;
    }
  }
  // reduce colsums across g (lane bits 4,5), then across wm via LDS
#pragma unroll
  for (int n = 0; n < 4; ++n) {
    sE[n] += __shfl_xor(sE[n], 16);
    sE[n] += __shfl_xor(sE[n], 32);
  }
  if (g == 0) {
#pragma unroll
    for (int n = 0; n < 4; ++n) sps[wm][wn*64 + n*16 + l15] = sE[n];
  }
  __syncthreads();
  if (wm == 0 && g == 0) {
#pragma unroll
    for (int n = 0; n < 4; ++n) {
      const int q64 = wn*64 + n*16 + l15;
      psw[((size_t)b * NQ + q64) * 8 + ct] = sps[0][q64] + sps[1][q64];
    }
  }
}

// ---------------------------------------------------------------------------
// K2 (fallback path only): P = E / sumE  (fp32 to out_a).
// ---------------------------------------------------------------------------
__global__ __launch_bounds__(256) void k2_scale(
    const _Float16* __restrict__ Ew, const float* __restrict__ psw,
    float* __restrict__ pout)
{
  const int row  = blockIdx.x * 4 + (threadIdx.x >> 6);
  const int lane = threadIdx.x & 63;

  float s = 0.f;
#pragma unroll
  for (int j = 0; j < 8; ++j) s += psw[(size_t)row * 8 + j];
  const float r = 1.0f / s;

  const _Float16* e = Ew + (size_t)row * NC;
  float* p = pout + (size_t)row * NC;
#pragma unroll
  for (int hseg = 0; hseg < 2; ++hseg) {
    f16x8 v = *(const f16x8*)&e[lane * 8 + hseg * 512];
    float4 lo, hi;
    lo.x = (float)v[0] * r;  lo.y = (float)v[1] * r;
    lo.z = (float)v[2] * r;  lo.w = (float)v[3] * r;
    hi.x = (float)v[4] * r;  hi.y = (float)v[5] * r;
    hi.z = (float)v[6] * r;  hi.w = (float)v[7] * r;
    *(float4*)&p[lane * 8 + hseg * 512]     = lo;
    *(float4*)&p[lane * 8 + hseg * 512 + 4] = hi;
  }
}

// ---------------------------------------------------------------------------
// K3e: wcontext[b][q][d] = rsu[q] * sum_c E[b][q][c] * ctx[b][c][d]
// A = E fp16 rows straight from ws (no cvt); B = ctx^T via reg transpose.
// Double-buffered LDS, one raw barrier per k-step. Reverse-b for L3 tail.
// ALSO emits P = fp32(E)*rsu for c-columns [dt*128, dt*128+128) from the
// staged E registers (k0-gated, balanced across blocks) -> replaces K2.
// ---------------------------------------------------------------------------
__global__ __launch_bounds__(256, 2) void k3_wctx_e(
    const _Float16* __restrict__ Ew, const float* __restrict__ psw,
    const float* __restrict__ ctx, float* __restrict__ wout,
    float* __restrict__ pout)
{
  __shared__ _Float16 Ps[2][128][72];  // E rows (q), k=c contiguous
  __shared__ _Float16 Cs[2][128][68];  // ctx^T rows (d), k=c contiguous
  __shared__ float rsu[128];           // 1/sumE per q

  int b, dt;
  remap(b, dt);
  b = NB - 1 - b;            // reverse: ride K1's L3 tail of ctx
  const int d0 = dt * 128;
  const int t  = threadIdx.x;
  const int lane = t & 63, wave = t >> 6;
  const int wm = wave >> 1, wn = wave & 1;
  const int g = lane >> 4, l15 = lane & 15;
  const int d4 = t & 31;      // d quad (0..31)
  const int cq0 = t >> 5;     // c quad base (0..7)
  const int rE = t >> 3;      // E-staging row (0..31, x4 passes)
  const int cE = (t & 7) * 8; // E-staging col base

  const float* ctxB = ctx + (size_t)b * NC * ND;
  const _Float16* Eb = Ew + (size_t)b * NQ * NC;

  if (t < 128) {
    const float* pp = &psw[((size_t)b * NQ + t) * 8];
    float4 a = *(const float4*)pp;
    float4 c4 = *(const float4*)(pp + 4);
    rsu[t] = 1.0f / (a.x + a.y + a.z + a.w + c4.x + c4.y + c4.z + c4.w);
  }

  f32x4 acc[4][4] = {};
  f16x8 eh[4];
  float4 rc[8];

  auto loadE = [&](int k0) {
#pragma unroll
    for (int r = 0; r < 4; ++r)
      eh[r] = *(const f16x8*)&Eb[(size_t)(r*32 + rE) * NC + k0 + cE];
  };
  auto loadB = [&](int k0) {
#pragma unroll
    for (int p = 0; p < 2; ++p) {
      const int cc = (cq0 + p*8) * 4;
#pragma unroll
      for (int j = 0; j < 4; ++j)
        rc[p*4 + j] = *(const float4*)&ctxB[(size_t)(k0 + cc + j) * ND + d0 + d4*4];
    }
  };

  loadE(0);
  loadB(0);
  __syncthreads();   // rsu visible before the P-emit in the first k-step

  // per-thread rsu for the 4 E-staging rows (for the P-emit)
  float rq4[4];
#pragma unroll
  for (int r = 0; r < 4; ++r) rq4[r] = rsu[r*32 + rE];
  float* Pb = pout + (size_t)b * NQ * NC;

  for (int k0 = 0; k0 < NC; k0 += 64) {
    const int buf = (k0 >> 6) & 1;
    // write phase
#pragma unroll
    for (int r = 0; r < 4; ++r)
      *(f16x8*)&Ps[buf][r*32 + rE][cE] = eh[r];
    // P-emit: this block owns c-columns [128dt, 128dt+128)
    if ((k0 >> 7) == dt) {
#pragma unroll
      for (int r = 0; r < 4; ++r) {
        f16x8 v = eh[r];
        const float rq = rq4[r];
        float4 lo, hi;
        lo.x = (float)v[0] * rq;  lo.y = (float)v[1] * rq;
        lo.z = (float)v[2] * rq;  lo.w = (float)v[3] * rq;
        hi.x = (float)v[4] * rq;  hi.y = (float)v[5] * rq;
        hi.z = (float)v[6] * rq;  hi.w = (float)v[7] * rq;
        float* dst = &Pb[(size_t)(r*32 + rE) * NC + k0 + cE];
        *(float4*)dst       = lo;
        *(float4*)(dst + 4) = hi;
      }
    }
#pragma unroll
    for (int p = 0; p < 2; ++p) {
      const int cc = (cq0 + p*8) * 4;
      float4 r0 = rc[p*4+0], r1 = rc[p*4+1], r2 = rc[p*4+2], r3 = rc[p*4+3];
      *(f16x4*)&Cs[buf][d4*4 + 0][cc] = cvtT(r0.x, r1.x, r2.x, r3.x);
      *(f16x4*)&Cs[buf][d4*4 + 1][cc] = cvtT(r0.y, r1.y, r2.y, r3.y);
      *(f16x4*)&Cs[buf][d4*4 + 2][cc] = cvtT(r0.z, r1.z, r2.z, r3.z);
      *(f16x4*)&Cs[buf][d4*4 + 3][cc] = cvtT(r0.w, r1.w, r2.w, r3.w);
    }
    if (k0 + 64 < NC) { loadE(k0 + 64); loadB(k0 + 64); }  // cross barrier
    pipe_barrier();
#pragma unroll
    for (int kk = 0; kk < 2; ++kk) {
      f16x8 af[4], bf[4];
#pragma unroll
      for (int m = 0; m < 4; ++m)
        af[m] = *(const f16x8*)&Ps[buf][wm*64 + m*16 + l15][kk*32 + g*8];
#pragma unroll
      for (int n = 0; n < 4; ++n) {
        const int rowd = wn*64 + n*16 + l15;
        f16x4 blo = *(const f16x4*)&Cs[buf][rowd][kk*32 + g*8];
        f16x4 bhi = *(const f16x4*)&Cs[buf][rowd][kk*32 + g*8 + 4];
        bf[n] = (f16x8){blo[0], blo[1], blo[2], blo[3],
                        bhi[0], bhi[1], bhi[2], bhi[3]};
      }
#pragma unroll
      for (int m = 0; m < 4; ++m)
#pragma unroll
        for (int n = 0; n < 4; ++n)
          acc[m][n] = __builtin_amdgcn_mfma_f32_16x16x32_f16(af[m], bf[n], acc[m][n], 0, 0, 0);
    }
  }

  float* wB = wout + (size_t)b * NQ * ND;
#pragma unroll
  for (int m = 0; m < 4; ++m) {
    const int qrow = wm*64 + m*16 + g*4;
#pragma unroll
    for (int n = 0; n < 4; ++n) {
      const int dd = d0 + wn*64 + n*16 + l15;
#pragma unroll
      for (int i = 0; i < 4; ++i)
        wB[(size_t)(qrow + i) * ND + dd] = acc[m][n][i] * rsu[qrow + i];
    }
  }
}

// ---------------------------------------------------------------------------
// K3p (fallback, R6-proven): W = P @ ctx with P fp32 from out_a. (Only used
// if ws is too small for E; evidence says ws ~= 2 GiB, so normally dead.)
// ---------------------------------------------------------------------------
__global__ __launch_bounds__(256, 2) void k3_wctx_p(
    const float* __restrict__ attn, const float* __restrict__ ctx,
    float* __restrict__ wout)
{
  __shared__ _Float16 Ps[128][72];
  __shared__ _Float16 Cs[128][68];

  int b, dt;
  remap(b, dt);
  const int d0 = dt * 128;
  const int t  = threadIdx.x;
  const int lane = t & 63, wave = t >> 6;
  const int wm = wave >> 1, wn = wave & 1;
  const int g = lane >> 4, l15 = lane & 15;
  const int lrow = t >> 4, lcol = (t & 15) * 4;
  const int d4 = t & 31;
  const int cq0 = t >> 5;

  const float* ctxB = ctx + (size_t)b * NC * ND;
  const float* pB   = attn + (size_t)b * NQ * NC;

  f32x4 acc[4][4] = {};
  float4 pa[8], rc[8];

  auto k3_load = [&](int k0) {
#pragma unroll
    for (int r = 0; r < 8; ++r)
      pa[r] = *(const float4*)&pB[(size_t)(r*16 + lrow) * NC + k0 + lcol];
#pragma unroll
    for (int p = 0; p < 2; ++p) {
      const int cc = (cq0 + p*8) * 4;
#pragma unroll
      for (int j = 0; j < 4; ++j)
        rc[p*4 + j] = *(const float4*)&ctxB[(size_t)(k0 + cc + j) * ND + d0 + d4*4];
    }
  };

  k3_load(0);
  for (int k0 = 0; k0 < NC; k0 += 64) {
#pragma unroll
    for (int r = 0; r < 8; ++r)
      *(f16x4*)&Ps[r*16 + lrow][lcol] = cvt4(pa[r]);
#pragma unroll
    for (int p = 0; p < 2; ++p) {
      const int cc = (cq0 + p*8) * 4;
      float4 r0 = rc[p*4+0], r1 = rc[p*4+1], r2 = rc[p*4+2], r3 = rc[p*4+3];
      *(f16x4*)&Cs[d4*4 + 0][cc] = cvtT(r0.x, r1.x, r2.x, r3.x);
      *(f16x4*)&Cs[d4*4 + 1][cc] = cvtT(r0.y, r1.y, r2.y, r3.y);
      *(f16x4*)&Cs[d4*4 + 2][cc] = cvtT(r0.z, r1.z, r2.z, r3.z);
      *(f16x4*)&Cs[d4*4 + 3][cc] = cvtT(r0.w, r1.w, r2.w, r3.w);
    }
    __syncthreads();
    if (k0 + 64 < NC) k3_load(k0 + 64);
#pragma unroll
    for (int kk = 0; kk < 2; ++kk) {
      f16x8 af[4], bf[4];
#pragma unroll
      for (int m = 0; m < 4; ++m)
        af[m] = *(const f16x8*)&Ps[wm*64 + m*16 + l15][kk*32 + g*8];
#pragma unroll
      for (int n = 0; n < 4; ++n) {
        const int rowd = wn*64 + n*16 + l15;
        f16x4 blo = *(const f16x4*)&Cs[rowd][kk*32 + g*8];
        f16x4 bhi = *(const f16x4*)&Cs[rowd][kk*32 + g*8 + 4];
        bf[n] = (f16x8){blo[0], blo[1], blo[2], blo[3],
                        bhi[0], bhi[1], bhi[2], bhi[3]};
      }
#pragma unroll
      for (int m = 0; m < 4; ++m)
#pragma unroll
        for (int n = 0; n < 4; ++n)
          acc[m][n] = __builtin_amdgcn_mfma_f32_16x16x32_f16(af[m], bf[n], acc[m][n], 0, 0, 0);
    }
    __syncthreads();
  }

  float* wB = wout + (size_t)b * NQ * ND;
#pragma unroll
  for (int m = 0; m < 4; ++m) {
    const int qrow = wm*64 + m*16 + g*4;
#pragma unroll
    for (int n = 0; n < 4; ++n) {
      const int dd = d0 + wn*64 + n*16 + l15;
#pragma unroll
      for (int i = 0; i < 4; ++i)
        wB[(size_t)(qrow + i) * ND + dd] = acc[m][n][i];
    }
  }
}

// ---------------------------------------------------------------------------
extern "C" void kernel_launch(void* const* d_in, const int* in_sizes, int n_in,
                              void* d_out, int out_size, void* d_ws, size_t ws_size,
                              hipStream_t stream)
{
  const float* qry = (const float*)d_in[0];
  const float* ctx = (const float*)d_in[1];
  float* out   = (float*)d_out;
  float* out_q = out;                                  // query passthrough
  float* out_w = out + (size_t)NB * NQ * ND;           // wcontext
  float* out_a = out + 2 * (size_t)NB * NQ * ND;       // attn (P)

  const size_t E_BYTES  = (size_t)NB * NQ * NC * sizeof(_Float16);   // 32 MiB
  const size_t PS_BYTES = (size_t)NB * NQ * 8 * sizeof(float);       // 512 KiB

  if (ws_size >= E_BYTES + PS_BYTES) {
    // E + ps in workspace; K3 consumes E directly and also emits P (no K2).
    _Float16* Ew = (_Float16*)d_ws;
    float* psw = (float*)((char*)d_ws + E_BYTES);
    k1_logits_exp<<<dim3(8, 128), 256, 0, stream>>>(qry, ctx, Ew, psw, out_q);
    k3_wctx_e<<<dim3(8, 128), 256, 0, stream>>>(Ew, psw, ctx, out_w, out_a);
  } else {
    // R6 fallback: E/ps scratch inside out_w, K3 consumes fp32 P from out_a.
    _Float16* Ew = (_Float16*)out_w;
    float* psw = out_w + (size_t)NB * NQ * NC / 2;
    k1_logits_exp<<<dim3(8, 128), 256, 0, stream>>>(qry, ctx, Ew, psw, out_q);
    k2_scale<<<dim3(4096), 256, 0, stream>>>(Ew, psw, out_a);
    k3_wctx_p<<<dim3(8, 128), 256, 0, stream>>>(out_a, ctx, out_w);
  }
}